// Round 1
// baseline (1774.280 us; speedup 1.0000x reference)
//
#include <hip/hip_runtime.h>
#include <math.h>

#define N_NODES 50000
#define N_EDGES 1600000
#define IN_DIM 16
#define HID 64

__device__ __forceinline__ float lrelu(float v) { return v > 0.f ? v : 0.2f * v; }

__device__ __forceinline__ float wave_reduce_sum(float v) {
    #pragma unroll
    for (int off = 32; off > 0; off >>= 1) v += __shfl_down(v, off, 64);
    return v;
}

// K1: h1 = x @ W1 ; alpha_s1/alpha_d1 reductions. One node per block (128 threads, 2 waves = 2 heads)
__global__ void k1_h1(const float* __restrict__ x, const float* __restrict__ W1,
                      const float* __restrict__ as1, const float* __restrict__ ad1,
                      float* __restrict__ h1, float* __restrict__ al_s, float* __restrict__ al_d) {
    int n = blockIdx.x;
    int j = threadIdx.x;            // 0..127 output channel
    float xv[IN_DIM];
    #pragma unroll
    for (int i = 0; i < IN_DIM; i++) xv[i] = x[n * IN_DIM + i];
    float acc = 0.f;
    #pragma unroll
    for (int i = 0; i < IN_DIM; i++) acc = fmaf(xv[i], W1[i * 128 + j], acc);
    h1[n * 128 + j] = acc;
    int head = j >> 6;              // wave id
    int c = j & 63;
    float ps = wave_reduce_sum(acc * as1[head * 64 + c]);
    float pd = wave_reduce_sum(acc * ad1[head * 64 + c]);
    if (c == 0) { al_s[n * 2 + head] = ps; al_d[n * 2 + head] = pd; }
}

// CSR build
__global__ void k_hist(const int* __restrict__ dst, int* __restrict__ deg) {
    int e = blockIdx.x * blockDim.x + threadIdx.x;
    if (e < N_EDGES) atomicAdd(&deg[dst[e]], 1);
}

#define SCAN_B 256
__global__ void k_scan1(const int* __restrict__ deg, int* __restrict__ off, int* __restrict__ bsum) {
    __shared__ int sh[SCAN_B];
    int gid = blockIdx.x * SCAN_B + threadIdx.x;
    int v = (gid < N_NODES) ? deg[gid] : 0;
    sh[threadIdx.x] = v;
    __syncthreads();
    for (int o = 1; o < SCAN_B; o <<= 1) {
        int t = (threadIdx.x >= o) ? sh[threadIdx.x - o] : 0;
        __syncthreads();
        sh[threadIdx.x] += t;
        __syncthreads();
    }
    int incl = sh[threadIdx.x];
    if (gid < N_NODES) off[gid] = incl - v;            // exclusive
    if (threadIdx.x == SCAN_B - 1) bsum[blockIdx.x] = incl;
}
__global__ void k_scan2(int* __restrict__ bsum, int nblocks) {
    __shared__ int sh[SCAN_B];
    int v = (threadIdx.x < nblocks) ? bsum[threadIdx.x] : 0;
    sh[threadIdx.x] = v;
    __syncthreads();
    for (int o = 1; o < SCAN_B; o <<= 1) {
        int t = (threadIdx.x >= o) ? sh[threadIdx.x - o] : 0;
        __syncthreads();
        sh[threadIdx.x] += t;
        __syncthreads();
    }
    if (threadIdx.x < nblocks) bsum[threadIdx.x] = sh[threadIdx.x] - v;  // exclusive
}
__global__ void k_scan3(int* __restrict__ off, const int* __restrict__ bsum, int* __restrict__ cursor) {
    int gid = blockIdx.x * SCAN_B + threadIdx.x;
    if (gid < N_NODES) {
        int o = off[gid] + bsum[blockIdx.x];
        off[gid] = o;
        cursor[gid] = o;
    }
    if (gid == 0) off[N_NODES] = N_EDGES;
}
__global__ void k_scatter(const int* __restrict__ src, const int* __restrict__ dst,
                          int* __restrict__ cursor, int* __restrict__ ssrc) {
    int e = blockIdx.x * blockDim.x + threadIdx.x;
    if (e < N_EDGES) {
        int d = dst[e];
        int pos = atomicAdd(&cursor[d], 1);
        ssrc[pos] = src[e];
    }
}

// K3: layer-1 GAT softmax-aggregation. 1 wave per node, lane = channel, 2 heads per lane.
__global__ void k3_agg1(const float* __restrict__ h1, const float* __restrict__ as,
                        const float* __restrict__ ad, const float* __restrict__ b1,
                        const int* __restrict__ off, const int* __restrict__ ssrc,
                        float* __restrict__ out1) {
    int wid = threadIdx.x >> 6, lane = threadIdx.x & 63;
    int d = blockIdx.x * 4 + wid;
    if (d >= N_NODES) return;
    int beg = off[d], end = off[d + 1];
    float ad0 = ad[d * 2 + 0], ad1v = ad[d * 2 + 1];
    float e0s = lrelu(as[d * 2 + 0] + ad0);
    float e1s = lrelu(as[d * 2 + 1] + ad1v);
    float m0 = e0s, m1 = e1s;
    for (int i = beg; i < end; i++) {
        int s = ssrc[i];
        m0 = fmaxf(m0, lrelu(as[s * 2 + 0] + ad0));
        m1 = fmaxf(m1, lrelu(as[s * 2 + 1] + ad1v));
    }
    float den0 = 0.f, den1 = 0.f, acc0 = 0.f, acc1 = 0.f;
    for (int i = beg; i < end; i++) {
        int s = ssrc[i];
        float w0 = __expf(lrelu(as[s * 2 + 0] + ad0) - m0);
        float w1 = __expf(lrelu(as[s * 2 + 1] + ad1v) - m1);
        den0 += w0; den1 += w1;
        acc0 = fmaf(w0, h1[s * 128 + lane], acc0);
        acc1 = fmaf(w1, h1[s * 128 + 64 + lane], acc1);
    }
    float w0 = __expf(e0s - m0), w1 = __expf(e1s - m1);
    den0 += w0; den1 += w1;
    acc0 = fmaf(w0, h1[d * 128 + lane], acc0);
    acc1 = fmaf(w1, h1[d * 128 + 64 + lane], acc1);
    out1[d * 128 + lane]      = fmaxf(acc0 / den0 + b1[lane], 0.f);
    out1[d * 128 + 64 + lane] = fmaxf(acc1 / den1 + b1[64 + lane], 0.f);
}

// K4: h2 = out1 @ W2 ; alpha_s2/alpha_d2. W2 staged in LDS. 1 wave per node.
__global__ void k4_h2(const float* __restrict__ out1, const float* __restrict__ W2,
                      const float* __restrict__ as2, const float* __restrict__ ad2,
                      float* __restrict__ h2, float* __restrict__ al_s, float* __restrict__ al_d) {
    __shared__ float w[128 * 64];
    for (int t = threadIdx.x; t < 128 * 64; t += blockDim.x) w[t] = W2[t];
    __syncthreads();
    int wid = threadIdx.x >> 6, lane = threadIdx.x & 63;
    int n = blockIdx.x * 4 + wid;
    if (n >= N_NODES) return;
    const float* r = out1 + n * 128;
    float acc = 0.f;
    #pragma unroll 8
    for (int k = 0; k < 128; k++) acc = fmaf(r[k], w[k * 64 + lane], acc);
    h2[n * 64 + lane] = acc;
    float ps = wave_reduce_sum(acc * as2[lane]);
    float pd = wave_reduce_sum(acc * ad2[lane]);
    if (lane == 0) { al_s[n] = ps; al_d[n] = pd; }
}

// K5: layer-2 GAT aggregation (1 head)
__global__ void k5_agg2(const float* __restrict__ h2, const float* __restrict__ as,
                        const float* __restrict__ ad, const float* __restrict__ b2,
                        const int* __restrict__ off, const int* __restrict__ ssrc,
                        float* __restrict__ out2) {
    int wid = threadIdx.x >> 6, lane = threadIdx.x & 63;
    int d = blockIdx.x * 4 + wid;
    if (d >= N_NODES) return;
    int beg = off[d], end = off[d + 1];
    float adv = ad[d];
    float es = lrelu(as[d] + adv);
    float m = es;
    for (int i = beg; i < end; i++) m = fmaxf(m, lrelu(as[ssrc[i]] + adv));
    float den = 0.f, acc = 0.f;
    for (int i = beg; i < end; i++) {
        int s = ssrc[i];
        float w = __expf(lrelu(as[s] + adv) - m);
        den += w;
        acc = fmaf(w, h2[s * 64 + lane], acc);
    }
    float w = __expf(es - m);
    den += w;
    acc = fmaf(w, h2[d * 64 + lane], acc);
    out2[d * 64 + lane] = fmaxf(acc / den + b2[lane], 0.f);
}

// K6: U = out2 @ mW1[0:64,:], V = out2 @ mW1[64:128,:]
__global__ void k6_uv(const float* __restrict__ out2, const float* __restrict__ mW1,
                      float* __restrict__ U, float* __restrict__ V) {
    __shared__ float w[128 * 64];
    for (int t = threadIdx.x; t < 128 * 64; t += blockDim.x) w[t] = mW1[t];
    __syncthreads();
    int wid = threadIdx.x >> 6, lane = threadIdx.x & 63;
    int n = blockIdx.x * 4 + wid;
    if (n >= N_NODES) return;
    const float* r = out2 + n * 64;
    float au = 0.f, av = 0.f;
    #pragma unroll 4
    for (int k = 0; k < 64; k++) {
        float rv = r[k];
        au = fmaf(rv, w[k * 64 + lane], au);
        av = fmaf(rv, w[(64 + k) * 64 + lane], av);
    }
    U[n * 64 + lane] = au;
    V[n * 64 + lane] = av;
}

// K7: edge MLP. Wave per edge (grid-stride). W2/W3 columns in VGPRs, z broadcast via LDS.
__global__ __launch_bounds__(256) void k7_mlp(
    const int* __restrict__ row, const int* __restrict__ col,
    const float* __restrict__ U, const float* __restrict__ V,
    const float* __restrict__ mb1,
    const float* __restrict__ mW2, const float* __restrict__ mb2,
    const float* __restrict__ mW3, const float* __restrict__ mb3,
    const float* __restrict__ mW4, const float* __restrict__ mb4,
    float* __restrict__ out) {
    int wid = threadIdx.x >> 6, lane = threadIdx.x & 63;
    __shared__ float zb1[4][64];
    __shared__ float zb2[4][64];
    float w2c[64], w3c[64];
    #pragma unroll
    for (int k = 0; k < 64; k++) { w2c[k] = mW2[k * 64 + lane]; w3c[k] = mW3[k * 64 + lane]; }
    float b1v = mb1[lane], b2v = mb2[lane], b3v = mb3[lane];
    float w4v = mW4[lane], b4v = mb4[0];
    int gw = blockIdx.x * 4 + wid;
    int nw = gridDim.x * 4;
    for (int e = gw; e < N_EDGES; e += nw) {
        int r = row[e], c = col[e];
        float z1 = fmaxf(U[r * 64 + lane] + V[c * 64 + lane] + b1v, 0.f);
        zb1[wid][lane] = z1;
        float acc = b2v;
        const float4* zp1 = (const float4*)(&zb1[wid][0]);
        #pragma unroll
        for (int k = 0; k < 16; k++) {
            float4 zz = zp1[k];
            acc = fmaf(zz.x, w2c[4 * k + 0], acc);
            acc = fmaf(zz.y, w2c[4 * k + 1], acc);
            acc = fmaf(zz.z, w2c[4 * k + 2], acc);
            acc = fmaf(zz.w, w2c[4 * k + 3], acc);
        }
        float z2 = fmaxf(acc, 0.f);
        zb2[wid][lane] = z2;
        acc = b3v;
        const float4* zp2 = (const float4*)(&zb2[wid][0]);
        #pragma unroll
        for (int k = 0; k < 16; k++) {
            float4 zz = zp2[k];
            acc = fmaf(zz.x, w3c[4 * k + 0], acc);
            acc = fmaf(zz.y, w3c[4 * k + 1], acc);
            acc = fmaf(zz.z, w3c[4 * k + 2], acc);
            acc = fmaf(zz.w, w3c[4 * k + 3], acc);
        }
        float z3 = fmaxf(acc, 0.f);
        float p = wave_reduce_sum(z3 * w4v);
        if (lane == 0) out[e] = p + b4v;
    }
}

extern "C" void kernel_launch(void* const* d_in, const int* in_sizes, int n_in,
                              void* d_out, int out_size, void* d_ws, size_t ws_size,
                              hipStream_t stream) {
    const float* x   = (const float*)d_in[0];
    const int*   ei  = (const int*)d_in[1];
    const float* W1  = (const float*)d_in[2];
    const float* as1 = (const float*)d_in[3];
    const float* ad1 = (const float*)d_in[4];
    const float* b1  = (const float*)d_in[5];
    const float* W2  = (const float*)d_in[6];
    const float* as2 = (const float*)d_in[7];
    const float* ad2 = (const float*)d_in[8];
    const float* b2  = (const float*)d_in[9];
    const float* mW1 = (const float*)d_in[10];
    const float* mb1 = (const float*)d_in[11];
    const float* mW2 = (const float*)d_in[12];
    const float* mb2 = (const float*)d_in[13];
    const float* mW3 = (const float*)d_in[14];
    const float* mb3 = (const float*)d_in[15];
    const float* mW4 = (const float*)d_in[16];
    const float* mb4 = (const float*)d_in[17];
    float* out = (float*)d_out;
    const int* row = ei;             // src
    const int* col = ei + N_EDGES;   // dst

    char* w = (char*)d_ws;
    // bufA: h1 -> h2 -> U|V ; bufB: out1 -> out2 (sequential reuse)
    float* bufA  = (float*)w;                        // 25,600,000 B
    float* bufB  = (float*)(w + 25600000);           // 25,600,000 B
    float* al_s1 = (float*)(w + 51200000);           // N*2 f32
    float* al_d1 = (float*)(w + 51600000);
    float* al_s2 = (float*)(w + 52000000);           // N f32
    float* al_d2 = (float*)(w + 52200000);
    int*   deg   = (int*)(w + 52400000);             // N
    int*   offp  = (int*)(w + 52600000);             // N+1
    int*   cursor= (int*)(w + 52800064);             // N
    int*   ssrc  = (int*)(w + 53000064);             // E
    int*   bsum  = (int*)(w + 59400064);             // 256

    hipMemsetAsync(deg, 0, N_NODES * sizeof(int), stream);
    k1_h1<<<N_NODES, 128, 0, stream>>>(x, W1, as1, ad1, bufA, al_s1, al_d1);
    k_hist<<<(N_EDGES + 255) / 256, 256, 0, stream>>>(col, deg);
    k_scan1<<<(N_NODES + SCAN_B - 1) / SCAN_B, SCAN_B, 0, stream>>>(deg, offp, bsum);
    k_scan2<<<1, SCAN_B, 0, stream>>>(bsum, (N_NODES + SCAN_B - 1) / SCAN_B);
    k_scan3<<<(N_NODES + SCAN_B - 1) / SCAN_B, SCAN_B, 0, stream>>>(offp, bsum, cursor);
    k_scatter<<<(N_EDGES + 255) / 256, 256, 0, stream>>>(row, col, cursor, ssrc);
    k3_agg1<<<N_NODES / 4, 256, 0, stream>>>(bufA, al_s1, al_d1, b1, offp, ssrc, bufB);
    k4_h2<<<N_NODES / 4, 256, 0, stream>>>(bufB, W2, as2, ad2, bufA, al_s2, al_d2);
    k5_agg2<<<N_NODES / 4, 256, 0, stream>>>(bufA, al_s2, al_d2, b2, offp, ssrc, bufB);
    k6_uv<<<N_NODES / 4, 256, 0, stream>>>(bufB, mW1, bufA, bufA + N_NODES * 64);
    k7_mlp<<<2048, 256, 0, stream>>>(row, col, bufA, bufA + N_NODES * 64, mb1,
                                     mW2, mb2, mW3, mb3, mW4, mb4, out);
}

// Round 2
// 1398.270 us; speedup vs baseline: 1.2689x; 1.2689x over previous
//
#include <hip/hip_runtime.h>
#include <math.h>

#define N_NODES 50000
#define N_EDGES 1600000
#define IN_DIM 16
#define HID 64

__device__ __forceinline__ float lrelu(float v) { return v > 0.f ? v : 0.2f * v; }

__device__ __forceinline__ float wave_reduce_sum(float v) {
    #pragma unroll
    for (int off = 32; off > 0; off >>= 1) v += __shfl_down(v, off, 64);
    return v;
}

// K1: h1 = x @ W1 ; alpha_s1/alpha_d1 reductions. One node per block (128 threads, 2 waves = 2 heads)
__global__ void k1_h1(const float* __restrict__ x, const float* __restrict__ W1,
                      const float* __restrict__ as1, const float* __restrict__ ad1,
                      float* __restrict__ h1, float* __restrict__ al_s, float* __restrict__ al_d) {
    int n = blockIdx.x;
    int j = threadIdx.x;            // 0..127 output channel
    float xv[IN_DIM];
    #pragma unroll
    for (int i = 0; i < IN_DIM; i++) xv[i] = x[n * IN_DIM + i];
    float acc = 0.f;
    #pragma unroll
    for (int i = 0; i < IN_DIM; i++) acc = fmaf(xv[i], W1[i * 128 + j], acc);
    h1[n * 128 + j] = acc;
    int head = j >> 6;              // wave id
    int c = j & 63;
    float ps = wave_reduce_sum(acc * as1[head * 64 + c]);
    float pd = wave_reduce_sum(acc * ad1[head * 64 + c]);
    if (c == 0) { al_s[n * 2 + head] = ps; al_d[n * 2 + head] = pd; }
}

// CSR build
__global__ void k_hist(const int* __restrict__ dst, int* __restrict__ deg) {
    int e = blockIdx.x * blockDim.x + threadIdx.x;
    if (e < N_EDGES) atomicAdd(&deg[dst[e]], 1);
}

#define SCAN_B 256
__global__ void k_scan1(const int* __restrict__ deg, int* __restrict__ off, int* __restrict__ bsum) {
    __shared__ int sh[SCAN_B];
    int gid = blockIdx.x * SCAN_B + threadIdx.x;
    int v = (gid < N_NODES) ? deg[gid] : 0;
    sh[threadIdx.x] = v;
    __syncthreads();
    for (int o = 1; o < SCAN_B; o <<= 1) {
        int t = (threadIdx.x >= o) ? sh[threadIdx.x - o] : 0;
        __syncthreads();
        sh[threadIdx.x] += t;
        __syncthreads();
    }
    int incl = sh[threadIdx.x];
    if (gid < N_NODES) off[gid] = incl - v;            // exclusive
    if (threadIdx.x == SCAN_B - 1) bsum[blockIdx.x] = incl;
}
__global__ void k_scan2(int* __restrict__ bsum, int nblocks) {
    __shared__ int sh[SCAN_B];
    int v = (threadIdx.x < nblocks) ? bsum[threadIdx.x] : 0;
    sh[threadIdx.x] = v;
    __syncthreads();
    for (int o = 1; o < SCAN_B; o <<= 1) {
        int t = (threadIdx.x >= o) ? sh[threadIdx.x - o] : 0;
        __syncthreads();
        sh[threadIdx.x] += t;
        __syncthreads();
    }
    if (threadIdx.x < nblocks) bsum[threadIdx.x] = sh[threadIdx.x] - v;  // exclusive
}
__global__ void k_scan3(int* __restrict__ off, const int* __restrict__ bsum, int* __restrict__ cursor) {
    int gid = blockIdx.x * SCAN_B + threadIdx.x;
    if (gid < N_NODES) {
        int o = off[gid] + bsum[blockIdx.x];
        off[gid] = o;
        cursor[gid] = o;
    }
    if (gid == 0) off[N_NODES] = N_EDGES;
}
__global__ void k_scatter(const int* __restrict__ src, const int* __restrict__ dst,
                          int* __restrict__ cursor, int* __restrict__ ssrc) {
    int e = blockIdx.x * blockDim.x + threadIdx.x;
    if (e < N_EDGES) {
        int d = dst[e];
        int pos = atomicAdd(&cursor[d], 1);
        ssrc[pos] = src[e];
    }
}

// K3: layer-1 GAT aggregation, ONLINE softmax (single pass over in-edges).
__global__ void k3_agg1(const float* __restrict__ h1, const float* __restrict__ as,
                        const float* __restrict__ ad, const float* __restrict__ b1,
                        const int* __restrict__ off, const int* __restrict__ ssrc,
                        float* __restrict__ out1) {
    int wid = threadIdx.x >> 6, lane = threadIdx.x & 63;
    int d = blockIdx.x * 4 + wid;
    if (d >= N_NODES) return;
    int beg = off[d], end = off[d + 1];
    float ad0 = ad[d * 2 + 0], ad1v = ad[d * 2 + 1];
    // self loop initializes running state: m=e_self, weight exp(0)=1
    float m0 = lrelu(as[d * 2 + 0] + ad0);
    float m1 = lrelu(as[d * 2 + 1] + ad1v);
    float den0 = 1.f, den1 = 1.f;
    float acc0 = h1[d * 128 + lane];
    float acc1 = h1[d * 128 + 64 + lane];
    for (int i = beg; i < end; i++) {
        int s = ssrc[i];
        float e0 = lrelu(as[s * 2 + 0] + ad0);
        float e1 = lrelu(as[s * 2 + 1] + ad1v);
        float h0 = h1[s * 128 + lane];
        float hv1 = h1[s * 128 + 64 + lane];
        float n0 = fmaxf(m0, e0), n1 = fmaxf(m1, e1);
        float f0 = __expf(m0 - n0), w0 = __expf(e0 - n0);
        float f1 = __expf(m1 - n1), w1 = __expf(e1 - n1);
        den0 = den0 * f0 + w0;  acc0 = acc0 * f0 + w0 * h0;
        den1 = den1 * f1 + w1;  acc1 = acc1 * f1 + w1 * hv1;
        m0 = n0; m1 = n1;
    }
    out1[d * 128 + lane]      = fmaxf(acc0 / den0 + b1[lane], 0.f);
    out1[d * 128 + 64 + lane] = fmaxf(acc1 / den1 + b1[64 + lane], 0.f);
}

// K4: h2 = out1 @ W2 ; alpha_s2/alpha_d2. W2 staged in LDS. 1 wave per node.
__global__ void k4_h2(const float* __restrict__ out1, const float* __restrict__ W2,
                      const float* __restrict__ as2, const float* __restrict__ ad2,
                      float* __restrict__ h2, float* __restrict__ al_s, float* __restrict__ al_d) {
    __shared__ float w[128 * 64];
    for (int t = threadIdx.x; t < 128 * 64; t += blockDim.x) w[t] = W2[t];
    __syncthreads();
    int wid = threadIdx.x >> 6, lane = threadIdx.x & 63;
    int n = blockIdx.x * 4 + wid;
    if (n >= N_NODES) return;
    const float* r = out1 + n * 128;
    float acc = 0.f;
    #pragma unroll 8
    for (int k = 0; k < 128; k++) acc = fmaf(r[k], w[k * 64 + lane], acc);
    h2[n * 64 + lane] = acc;
    float ps = wave_reduce_sum(acc * as2[lane]);
    float pd = wave_reduce_sum(acc * ad2[lane]);
    if (lane == 0) { al_s[n] = ps; al_d[n] = pd; }
}

// K5: layer-2 GAT aggregation (1 head), online softmax single pass
__global__ void k5_agg2(const float* __restrict__ h2, const float* __restrict__ as,
                        const float* __restrict__ ad, const float* __restrict__ b2,
                        const int* __restrict__ off, const int* __restrict__ ssrc,
                        float* __restrict__ out2) {
    int wid = threadIdx.x >> 6, lane = threadIdx.x & 63;
    int d = blockIdx.x * 4 + wid;
    if (d >= N_NODES) return;
    int beg = off[d], end = off[d + 1];
    float adv = ad[d];
    float m = lrelu(as[d] + adv);
    float den = 1.f;
    float acc = h2[d * 64 + lane];
    for (int i = beg; i < end; i++) {
        int s = ssrc[i];
        float e = lrelu(as[s] + adv);
        float hv = h2[s * 64 + lane];
        float n = fmaxf(m, e);
        float f = __expf(m - n), w = __expf(e - n);
        den = den * f + w;  acc = acc * f + w * hv;
        m = n;
    }
    out2[d * 64 + lane] = fmaxf(acc / den + b2[lane], 0.f);
}

// K6: U = out2 @ mW1[0:64,:], V = out2 @ mW1[64:128,:]
__global__ void k6_uv(const float* __restrict__ out2, const float* __restrict__ mW1,
                      float* __restrict__ U, float* __restrict__ V) {
    __shared__ float w[128 * 64];
    for (int t = threadIdx.x; t < 128 * 64; t += blockDim.x) w[t] = mW1[t];
    __syncthreads();
    int wid = threadIdx.x >> 6, lane = threadIdx.x & 63;
    int n = blockIdx.x * 4 + wid;
    if (n >= N_NODES) return;
    const float* r = out2 + n * 64;
    float au = 0.f, av = 0.f;
    #pragma unroll 4
    for (int k = 0; k < 64; k++) {
        float rv = r[k];
        au = fmaf(rv, w[k * 64 + lane], au);
        av = fmaf(rv, w[(64 + k) * 64 + lane], av);
    }
    U[n * 64 + lane] = au;
    V[n * 64 + lane] = av;
}

// transpose mW2 (64x64) -> W2t so columns become contiguous rows (s_load friendly)
__global__ void k_w2t(const float* __restrict__ mW2, float* __restrict__ W2t) {
    int j = blockIdx.x, k = threadIdx.x;
    W2t[j * 64 + k] = mW2[k * 64 + j];
}

// K7b: edge MLP, lane = edge. 64 edges per wave, 2 waves/block.
// Weights are read at lane-invariant addresses -> compiler emits s_load + v_fmac with SGPR operand.
// Layer3 is accumulated as outer product (z2 scalar into 64 static regs) -> no z2 storage.
__global__ __launch_bounds__(128) void k7b_mlp(
    const int* __restrict__ row, const int* __restrict__ col,
    const float* __restrict__ U, const float* __restrict__ V,
    const float* __restrict__ mb1,
    const float* __restrict__ W2t, const float* __restrict__ mb2,
    const float* __restrict__ mW3, const float* __restrict__ mb3,
    const float* __restrict__ mW4, const float* __restrict__ mb4,
    float* __restrict__ out) {
    __shared__ float Z[2][64][68];     // pad 68: b32 writes and b128 reads both at LDS peak
    int wid = threadIdx.x >> 6, lane = threadIdx.x & 63;
    int ebase = blockIdx.x * 128 + wid * 64;
    int r_e = row[ebase + lane];
    int c_e = col[ebase + lane];
    float b1v = mb1[lane];

    // phase 1: z1 for 64 edges, edge-major (lane = channel), batched loads
    for (int i0 = 0; i0 < 64; i0 += 8) {
        float u[8], v[8];
        #pragma unroll
        for (int t = 0; t < 8; t++) {
            int ri = __builtin_amdgcn_readlane(r_e, i0 + t);
            int ci = __builtin_amdgcn_readlane(c_e, i0 + t);
            u[t] = U[ri * 64 + lane];
            v[t] = V[ci * 64 + lane];
        }
        #pragma unroll
        for (int t = 0; t < 8; t++)
            Z[wid][i0 + t][lane] = fmaxf(u[t] + v[t] + b1v, 0.f);
    }
    __syncthreads();

    // phase 2: transpose read — this thread owns edge (ebase+lane), row Z[wid][lane][:]
    float z1r[64];
    #pragma unroll
    for (int q = 0; q < 16; q++) {
        float4 t = *(const float4*)&Z[wid][lane][q * 4];
        z1r[q * 4 + 0] = t.x; z1r[q * 4 + 1] = t.y;
        z1r[q * 4 + 2] = t.z; z1r[q * 4 + 3] = t.w;
    }
    float z3a[64];
    #pragma unroll
    for (int i = 0; i < 64; i++) z3a[i] = 0.f;

    #pragma unroll 1
    for (int j = 0; j < 64; j++) {
        const float* w2r = W2t + j * 64;   // column j of mW2, contiguous
        float a0 = mb2[j], a1 = 0.f, a2 = 0.f, a3 = 0.f;
        #pragma unroll
        for (int k = 0; k < 16; k++) {
            a0 = fmaf(z1r[k],      w2r[k],      a0);
            a1 = fmaf(z1r[16 + k], w2r[16 + k], a1);
            a2 = fmaf(z1r[32 + k], w2r[32 + k], a2);
            a3 = fmaf(z1r[48 + k], w2r[48 + k], a3);
        }
        float z2 = fmaxf((a0 + a1) + (a2 + a3), 0.f);
        const float* w3r = mW3 + j * 64;   // row j of mW3, contiguous
        #pragma unroll
        for (int i = 0; i < 64; i++) z3a[i] = fmaf(z2, w3r[i], z3a[i]);
    }

    float s0 = 0.f, s1 = 0.f;
    #pragma unroll
    for (int i = 0; i < 32; i++) {
        s0 = fmaf(mW4[i],      fmaxf(z3a[i]      + mb3[i],      0.f), s0);
        s1 = fmaf(mW4[32 + i], fmaxf(z3a[32 + i] + mb3[32 + i], 0.f), s1);
    }
    out[ebase + lane] = s0 + s1 + mb4[0];
}

extern "C" void kernel_launch(void* const* d_in, const int* in_sizes, int n_in,
                              void* d_out, int out_size, void* d_ws, size_t ws_size,
                              hipStream_t stream) {
    const float* x   = (const float*)d_in[0];
    const int*   ei  = (const int*)d_in[1];
    const float* W1  = (const float*)d_in[2];
    const float* as1 = (const float*)d_in[3];
    const float* ad1 = (const float*)d_in[4];
    const float* b1  = (const float*)d_in[5];
    const float* W2  = (const float*)d_in[6];
    const float* as2 = (const float*)d_in[7];
    const float* ad2 = (const float*)d_in[8];
    const float* b2  = (const float*)d_in[9];
    const float* mW1 = (const float*)d_in[10];
    const float* mb1 = (const float*)d_in[11];
    const float* mW2 = (const float*)d_in[12];
    const float* mb2 = (const float*)d_in[13];
    const float* mW3 = (const float*)d_in[14];
    const float* mb3 = (const float*)d_in[15];
    const float* mW4 = (const float*)d_in[16];
    const float* mb4 = (const float*)d_in[17];
    float* out = (float*)d_out;
    const int* row = ei;             // src
    const int* col = ei + N_EDGES;   // dst

    char* w = (char*)d_ws;
    // bufA: h1 -> h2 -> U|V ; bufB: out1 -> out2 -> W2t (sequential reuse)
    float* bufA  = (float*)w;                        // 25,600,000 B
    float* bufB  = (float*)(w + 25600000);           // 25,600,000 B
    float* al_s1 = (float*)(w + 51200000);           // N*2 f32
    float* al_d1 = (float*)(w + 51600000);
    float* al_s2 = (float*)(w + 52000000);           // N f32
    float* al_d2 = (float*)(w + 52200000);
    int*   deg   = (int*)(w + 52400000);             // N
    int*   offp  = (int*)(w + 52600000);             // N+1
    int*   cursor= (int*)(w + 52800064);             // N
    int*   ssrc  = (int*)(w + 53000064);             // E
    int*   bsum  = (int*)(w + 59400064);             // 256

    hipMemsetAsync(deg, 0, N_NODES * sizeof(int), stream);
    k1_h1<<<N_NODES, 128, 0, stream>>>(x, W1, as1, ad1, bufA, al_s1, al_d1);
    k_hist<<<(N_EDGES + 255) / 256, 256, 0, stream>>>(col, deg);
    k_scan1<<<(N_NODES + SCAN_B - 1) / SCAN_B, SCAN_B, 0, stream>>>(deg, offp, bsum);
    k_scan2<<<1, SCAN_B, 0, stream>>>(bsum, (N_NODES + SCAN_B - 1) / SCAN_B);
    k_scan3<<<(N_NODES + SCAN_B - 1) / SCAN_B, SCAN_B, 0, stream>>>(offp, bsum, cursor);
    k_scatter<<<(N_EDGES + 255) / 256, 256, 0, stream>>>(row, col, cursor, ssrc);
    k3_agg1<<<N_NODES / 4, 256, 0, stream>>>(bufA, al_s1, al_d1, b1, offp, ssrc, bufB);
    k4_h2<<<N_NODES / 4, 256, 0, stream>>>(bufB, W2, as2, ad2, bufA, al_s2, al_d2);
    k5_agg2<<<N_NODES / 4, 256, 0, stream>>>(bufA, al_s2, al_d2, b2, offp, ssrc, bufB);
    k6_uv<<<N_NODES / 4, 256, 0, stream>>>(bufB, mW1, bufA, bufA + N_NODES * 64);
    float* W2t = bufB;  // bufB free after k6 consumed out2
    k_w2t<<<64, 64, 0, stream>>>(mW2, W2t);
    k7b_mlp<<<N_EDGES / 128, 128, 0, stream>>>(row, col, bufA, bufA + N_NODES * 64, mb1,
                                               W2t, mb2, mW3, mb3, mW4, mb4, out);
}

// Round 3
// 1056.704 us; speedup vs baseline: 1.6791x; 1.3232x over previous
//
#include <hip/hip_runtime.h>
#include <hip/hip_bf16.h>
#include <math.h>

#define N_NODES 50000
#define N_EDGES 1600000
#define IN_DIM 16
#define HID 64

typedef __attribute__((ext_vector_type(8))) short short8v;
typedef __attribute__((ext_vector_type(16))) float f32x16;

union U32x4S8 { unsigned u[4]; short8v s; };

__device__ __forceinline__ float lrelu(float v) { return v > 0.f ? v : 0.2f * v; }

__device__ __forceinline__ float wave_reduce_sum(float v) {
    #pragma unroll
    for (int off = 32; off > 0; off >>= 1) v += __shfl_down(v, off, 64);
    return v;
}

__device__ __forceinline__ unsigned pk_bf16(float a, float b) {
    unsigned ua = (unsigned)__bfloat16_as_ushort(__float2bfloat16(a));
    unsigned ub = (unsigned)__bfloat16_as_ushort(__float2bfloat16(b));
    return ua | (ub << 16);
}

// round-to-nearest bf16 hi + exact residual lo, packed pairs
__device__ __forceinline__ void hilo2(float f0, float f1, unsigned& hw, unsigned& lw) {
    __hip_bfloat16 h0 = __float2bfloat16(f0), h1 = __float2bfloat16(f1);
    float r0 = __bfloat162float(h0), r1 = __bfloat162float(h1);
    hw = (unsigned)__bfloat16_as_ushort(h0) | ((unsigned)__bfloat16_as_ushort(h1) << 16);
    lw = pk_bf16(f0 - r0, f1 - r1);
}

// K1: h1 = x @ W1 ; alpha_s1/alpha_d1 reductions.
__global__ void k1_h1(const float* __restrict__ x, const float* __restrict__ W1,
                      const float* __restrict__ as1, const float* __restrict__ ad1,
                      float* __restrict__ h1, float* __restrict__ al_s, float* __restrict__ al_d) {
    int n = blockIdx.x;
    int j = threadIdx.x;
    float xv[IN_DIM];
    #pragma unroll
    for (int i = 0; i < IN_DIM; i++) xv[i] = x[n * IN_DIM + i];
    float acc = 0.f;
    #pragma unroll
    for (int i = 0; i < IN_DIM; i++) acc = fmaf(xv[i], W1[i * 128 + j], acc);
    h1[n * 128 + j] = acc;
    int head = j >> 6;
    int c = j & 63;
    float ps = wave_reduce_sum(acc * as1[head * 64 + c]);
    float pd = wave_reduce_sum(acc * ad1[head * 64 + c]);
    if (c == 0) { al_s[n * 2 + head] = ps; al_d[n * 2 + head] = pd; }
}

// CSR build
__global__ void k_hist(const int* __restrict__ dst, int* __restrict__ deg) {
    int e = blockIdx.x * blockDim.x + threadIdx.x;
    if (e < N_EDGES) atomicAdd(&deg[dst[e]], 1);
}

#define SCAN_B 256
__global__ void k_scan1(const int* __restrict__ deg, int* __restrict__ off, int* __restrict__ bsum) {
    __shared__ int sh[SCAN_B];
    int gid = blockIdx.x * SCAN_B + threadIdx.x;
    int v = (gid < N_NODES) ? deg[gid] : 0;
    sh[threadIdx.x] = v;
    __syncthreads();
    for (int o = 1; o < SCAN_B; o <<= 1) {
        int t = (threadIdx.x >= o) ? sh[threadIdx.x - o] : 0;
        __syncthreads();
        sh[threadIdx.x] += t;
        __syncthreads();
    }
    int incl = sh[threadIdx.x];
    if (gid < N_NODES) off[gid] = incl - v;
    if (threadIdx.x == SCAN_B - 1) bsum[blockIdx.x] = incl;
}
__global__ void k_scan2(int* __restrict__ bsum, int nblocks) {
    __shared__ int sh[SCAN_B];
    int v = (threadIdx.x < nblocks) ? bsum[threadIdx.x] : 0;
    sh[threadIdx.x] = v;
    __syncthreads();
    for (int o = 1; o < SCAN_B; o <<= 1) {
        int t = (threadIdx.x >= o) ? sh[threadIdx.x - o] : 0;
        __syncthreads();
        sh[threadIdx.x] += t;
        __syncthreads();
    }
    if (threadIdx.x < nblocks) bsum[threadIdx.x] = sh[threadIdx.x] - v;
}
__global__ void k_scan3(int* __restrict__ off, const int* __restrict__ bsum, int* __restrict__ cursor) {
    int gid = blockIdx.x * SCAN_B + threadIdx.x;
    if (gid < N_NODES) {
        int o = off[gid] + bsum[blockIdx.x];
        off[gid] = o;
        cursor[gid] = o;
    }
    if (gid == 0) off[N_NODES] = N_EDGES;
}
__global__ void k_scatter(const int* __restrict__ src, const int* __restrict__ dst,
                          int* __restrict__ cursor, int* __restrict__ ssrc) {
    int e = blockIdx.x * blockDim.x + threadIdx.x;
    if (e < N_EDGES) {
        int d = dst[e];
        int pos = atomicAdd(&cursor[d], 1);
        ssrc[pos] = src[e];
    }
}

// K3: layer-1 GAT aggregation, online softmax
__global__ void k3_agg1(const float* __restrict__ h1, const float* __restrict__ as,
                        const float* __restrict__ ad, const float* __restrict__ b1,
                        const int* __restrict__ off, const int* __restrict__ ssrc,
                        float* __restrict__ out1) {
    int wid = threadIdx.x >> 6, lane = threadIdx.x & 63;
    int d = blockIdx.x * 4 + wid;
    if (d >= N_NODES) return;
    int beg = off[d], end = off[d + 1];
    float ad0 = ad[d * 2 + 0], ad1v = ad[d * 2 + 1];
    float m0 = lrelu(as[d * 2 + 0] + ad0);
    float m1 = lrelu(as[d * 2 + 1] + ad1v);
    float den0 = 1.f, den1 = 1.f;
    float acc0 = h1[d * 128 + lane];
    float acc1 = h1[d * 128 + 64 + lane];
    for (int i = beg; i < end; i++) {
        int s = ssrc[i];
        float e0 = lrelu(as[s * 2 + 0] + ad0);
        float e1 = lrelu(as[s * 2 + 1] + ad1v);
        float h0 = h1[s * 128 + lane];
        float hv1 = h1[s * 128 + 64 + lane];
        float n0 = fmaxf(m0, e0), n1 = fmaxf(m1, e1);
        float f0 = __expf(m0 - n0), w0 = __expf(e0 - n0);
        float f1 = __expf(m1 - n1), w1 = __expf(e1 - n1);
        den0 = den0 * f0 + w0;  acc0 = acc0 * f0 + w0 * h0;
        den1 = den1 * f1 + w1;  acc1 = acc1 * f1 + w1 * hv1;
        m0 = n0; m1 = n1;
    }
    out1[d * 128 + lane]      = fmaxf(acc0 / den0 + b1[lane], 0.f);
    out1[d * 128 + 64 + lane] = fmaxf(acc1 / den1 + b1[64 + lane], 0.f);
}

// K4: h2 = out1 @ W2 ; alpha_s2/alpha_d2
__global__ void k4_h2(const float* __restrict__ out1, const float* __restrict__ W2,
                      const float* __restrict__ as2, const float* __restrict__ ad2,
                      float* __restrict__ h2, float* __restrict__ al_s, float* __restrict__ al_d) {
    __shared__ float w[128 * 64];
    for (int t = threadIdx.x; t < 128 * 64; t += blockDim.x) w[t] = W2[t];
    __syncthreads();
    int wid = threadIdx.x >> 6, lane = threadIdx.x & 63;
    int n = blockIdx.x * 4 + wid;
    if (n >= N_NODES) return;
    const float* r = out1 + n * 128;
    float acc = 0.f;
    #pragma unroll 8
    for (int k = 0; k < 128; k++) acc = fmaf(r[k], w[k * 64 + lane], acc);
    h2[n * 64 + lane] = acc;
    float ps = wave_reduce_sum(acc * as2[lane]);
    float pd = wave_reduce_sum(acc * ad2[lane]);
    if (lane == 0) { al_s[n] = ps; al_d[n] = pd; }
}

// K5: layer-2 GAT aggregation, online softmax
__global__ void k5_agg2(const float* __restrict__ h2, const float* __restrict__ as,
                        const float* __restrict__ ad, const float* __restrict__ b2,
                        const int* __restrict__ off, const int* __restrict__ ssrc,
                        float* __restrict__ out2) {
    int wid = threadIdx.x >> 6, lane = threadIdx.x & 63;
    int d = blockIdx.x * 4 + wid;
    if (d >= N_NODES) return;
    int beg = off[d], end = off[d + 1];
    float adv = ad[d];
    float m = lrelu(as[d] + adv);
    float den = 1.f;
    float acc = h2[d * 64 + lane];
    for (int i = beg; i < end; i++) {
        int s = ssrc[i];
        float e = lrelu(as[s] + adv);
        float hv = h2[s * 64 + lane];
        float n = fmaxf(m, e);
        float f = __expf(m - n), w = __expf(e - n);
        den = den * f + w;  acc = acc * f + w * hv;
        m = n;
    }
    out2[d * 64 + lane] = fmaxf(acc / den + b2[lane], 0.f);
}

// K6: U = out2 @ mW1[0:64,:] + mb1 (bias folded), V = out2 @ mW1[64:128,:]
__global__ void k6_uv(const float* __restrict__ out2, const float* __restrict__ mW1,
                      const float* __restrict__ mb1,
                      float* __restrict__ U, float* __restrict__ V) {
    __shared__ float w[128 * 64];
    for (int t = threadIdx.x; t < 128 * 64; t += blockDim.x) w[t] = mW1[t];
    __syncthreads();
    int wid = threadIdx.x >> 6, lane = threadIdx.x & 63;
    int n = blockIdx.x * 4 + wid;
    if (n >= N_NODES) return;
    const float* r = out2 + n * 64;
    float au = 0.f, av = 0.f;
    #pragma unroll 4
    for (int k = 0; k < 64; k++) {
        float rv = r[k];
        au = fmaf(rv, w[k * 64 + lane], au);
        av = fmaf(rv, w[(64 + k) * 64 + lane], av);
    }
    U[n * 64 + lane] = au + mb1[lane];
    V[n * 64 + lane] = av;
}

// weight prep: W{2,3}t[b][t] = mW{2,3}[t*64+b] split into bf16 hi/lo tables
__global__ void k_wprep(const float* __restrict__ mW2, const float* __restrict__ mW3,
                        unsigned short* __restrict__ W2th, unsigned short* __restrict__ W2tl,
                        unsigned short* __restrict__ W3th, unsigned short* __restrict__ W3tl) {
    int b = blockIdx.x, t = threadIdx.x;
    float w2 = mW2[t * 64 + b];
    __hip_bfloat16 h2 = __float2bfloat16(w2);
    W2th[b * 64 + t] = __bfloat16_as_ushort(h2);
    W2tl[b * 64 + t] = __bfloat16_as_ushort(__float2bfloat16(w2 - __bfloat162float(h2)));
    float w3 = mW3[t * 64 + b];
    __hip_bfloat16 h3 = __float2bfloat16(w3);
    W3th[b * 64 + t] = __bfloat16_as_ushort(h3);
    W3tl[b * 64 + t] = __bfloat16_as_ushort(__float2bfloat16(w3 - __bfloat162float(h3)));
}

// K7c: edge MLP via MFMA (bf16 hi/lo split, 4-product exact-ish).
// Per wave: 64 edges. Layer2: D2 = W2t @ Z1^T (j x e), Layer3: D3 = W3t @ Z2^T (i x e).
// C/D layout (verified): col = lane&31, row = (reg&3)+8*(reg>>2)+4*(lane>>5).
__global__ __launch_bounds__(256) void k7c_mlp(
    const int* __restrict__ row, const int* __restrict__ col,
    const float* __restrict__ Ub, const float* __restrict__ Vb,
    const unsigned short* __restrict__ W2th, const unsigned short* __restrict__ W2tl,
    const unsigned short* __restrict__ W3th, const unsigned short* __restrict__ W3tl,
    const float* __restrict__ mb2, const float* __restrict__ mb3,
    const float* __restrict__ mW4, const float* __restrict__ mb4,
    float* __restrict__ out)
{
    const int wid = threadIdx.x >> 6, lane = threadIdx.x & 63;
    const int ebase = blockIdx.x * 256 + wid * 64;
    const int l31 = lane & 31;
    const int h = lane >> 5;          // which k-half / row-half this lane serves
    const int ksub = h * 8;

    int rfull = row[ebase + lane];
    int cfull = col[ebase + lane];
    float b4v = mb4[0];

    // w4 fragment (rows this lane owns in C/D layout)
    float w4f[2][16];
    #pragma unroll
    for (int mA = 0; mA < 2; mA++)
        #pragma unroll
        for (int r = 0; r < 16; r++)
            w4f[mA][r] = mW4[mA * 32 + (r & 3) + 8 * (r >> 2) + 4 * h];

    #pragma unroll 1
    for (int nB = 0; nB < 2; nB++) {
        int rA = __shfl(rfull, nB * 32 + l31, 64);
        int cA = __shfl(cfull, nB * 32 + l31, 64);
        const float* urow = Ub + rA * 64 + ksub;
        const float* vrow = Vb + cA * 64 + ksub;

        // layer-2 accumulators, bias-initialized
        f32x16 c2[2];
        #pragma unroll
        for (int mA = 0; mA < 2; mA++)
            #pragma unroll
            for (int r = 0; r < 16; r++)
                c2[mA][r] = mb2[mA * 32 + (r & 3) + 8 * (r >> 2) + 4 * h];

        #pragma unroll
        for (int kb = 0; kb < 4; kb++) {
            float4 u0 = *(const float4*)(urow + kb * 16);
            float4 u1 = *(const float4*)(urow + kb * 16 + 4);
            float4 v0 = *(const float4*)(vrow + kb * 16);
            float4 v1 = *(const float4*)(vrow + kb * 16 + 4);
            float z[8];
            z[0] = fmaxf(u0.x + v0.x, 0.f); z[1] = fmaxf(u0.y + v0.y, 0.f);
            z[2] = fmaxf(u0.z + v0.z, 0.f); z[3] = fmaxf(u0.w + v0.w, 0.f);
            z[4] = fmaxf(u1.x + v1.x, 0.f); z[5] = fmaxf(u1.y + v1.y, 0.f);
            z[6] = fmaxf(u1.z + v1.z, 0.f); z[7] = fmaxf(u1.w + v1.w, 0.f);
            U32x4S8 bh, bl;
            #pragma unroll
            for (int q = 0; q < 4; q++) hilo2(z[2 * q], z[2 * q + 1], bh.u[q], bl.u[q]);
            #pragma unroll
            for (int mA = 0; mA < 2; mA++) {
                const int wrow = (mA * 32 + l31) * 64 + kb * 16 + ksub;
                short8v ah = *(const short8v*)(W2th + wrow);
                short8v al = *(const short8v*)(W2tl + wrow);
                c2[mA] = __builtin_amdgcn_mfma_f32_32x32x16_bf16(ah, bh.s, c2[mA], 0, 0, 0);
                c2[mA] = __builtin_amdgcn_mfma_f32_32x32x16_bf16(al, bh.s, c2[mA], 0, 0, 0);
                c2[mA] = __builtin_amdgcn_mfma_f32_32x32x16_bf16(ah, bl.s, c2[mA], 0, 0, 0);
                c2[mA] = __builtin_amdgcn_mfma_f32_32x32x16_bf16(al, bl.s, c2[mA], 0, 0, 0);
            }
        }

        // z2 = relu(c2); re-fragment (j x e) -> B-operand of layer 3
        float zr[2][16];
        #pragma unroll
        for (int mA = 0; mA < 2; mA++)
            #pragma unroll
            for (int r = 0; r < 16; r++)
                zr[mA][r] = fmaxf(c2[mA][r], 0.f);

        unsigned B3h[4][4], B3l[4][4];
        #pragma unroll
        for (int kbp = 0; kbp < 4; kbp++) {
            const int mAs = kbp >> 1, kbl = kbp & 1;
            float e[8];
            #pragma unroll
            for (int b = 0; b < 4; b++) {
                float u = zr[mAs][8 * kbl + b];
                float v = zr[mAs][8 * kbl + 4 + b];
                float su = __shfl_xor(u, 32, 64);
                float sv = __shfl_xor(v, 32, 64);
                e[b]     = h ? sv : u;
                e[4 + b] = h ? v : su;
            }
            #pragma unroll
            for (int q = 0; q < 4; q++) hilo2(e[2 * q], e[2 * q + 1], B3h[kbp][q], B3l[kbp][q]);
        }

        // layer-3 accumulators, bias-initialized
        f32x16 c3[2];
        #pragma unroll
        for (int mA = 0; mA < 2; mA++)
            #pragma unroll
            for (int r = 0; r < 16; r++)
                c3[mA][r] = mb3[mA * 32 + (r & 3) + 8 * (r >> 2) + 4 * h];

        #pragma unroll
        for (int kbp = 0; kbp < 4; kbp++) {
            U32x4S8 bh, bl;
            #pragma unroll
            for (int q = 0; q < 4; q++) { bh.u[q] = B3h[kbp][q]; bl.u[q] = B3l[kbp][q]; }
            #pragma unroll
            for (int mA = 0; mA < 2; mA++) {
                const int wrow = (mA * 32 + l31) * 64 + kbp * 16 + ksub;
                short8v ah = *(const short8v*)(W3th + wrow);
                short8v al = *(const short8v*)(W3tl + wrow);
                c3[mA] = __builtin_amdgcn_mfma_f32_32x32x16_bf16(ah, bh.s, c3[mA], 0, 0, 0);
                c3[mA] = __builtin_amdgcn_mfma_f32_32x32x16_bf16(al, bh.s, c3[mA], 0, 0, 0);
                c3[mA] = __builtin_amdgcn_mfma_f32_32x32x16_bf16(ah, bl.s, c3[mA], 0, 0, 0);
                c3[mA] = __builtin_amdgcn_mfma_f32_32x32x16_bf16(al, bl.s, c3[mA], 0, 0, 0);
            }
        }

        float p = 0.f;
        #pragma unroll
        for (int mA = 0; mA < 2; mA++)
            #pragma unroll
            for (int r = 0; r < 16; r++)
                p = fmaf(fmaxf(c3[mA][r], 0.f), w4f[mA][r], p);
        p += __shfl_xor(p, 32, 64);
        if (lane < 32) out[ebase + nB * 32 + lane] = p + b4v;
    }
}

extern "C" void kernel_launch(void* const* d_in, const int* in_sizes, int n_in,
                              void* d_out, int out_size, void* d_ws, size_t ws_size,
                              hipStream_t stream) {
    const float* x   = (const float*)d_in[0];
    const int*   ei  = (const int*)d_in[1];
    const float* W1  = (const float*)d_in[2];
    const float* as1 = (const float*)d_in[3];
    const float* ad1 = (const float*)d_in[4];
    const float* b1  = (const float*)d_in[5];
    const float* W2  = (const float*)d_in[6];
    const float* as2 = (const float*)d_in[7];
    const float* ad2 = (const float*)d_in[8];
    const float* b2  = (const float*)d_in[9];
    const float* mW1 = (const float*)d_in[10];
    const float* mb1 = (const float*)d_in[11];
    const float* mW2 = (const float*)d_in[12];
    const float* mb2 = (const float*)d_in[13];
    const float* mW3 = (const float*)d_in[14];
    const float* mb3 = (const float*)d_in[15];
    const float* mW4 = (const float*)d_in[16];
    const float* mb4 = (const float*)d_in[17];
    float* out = (float*)d_out;
    const int* row = ei;
    const int* col = ei + N_EDGES;

    char* w = (char*)d_ws;
    float* bufA  = (float*)w;                        // h1 -> h2 -> U|V
    float* bufB  = (float*)(w + 25600000);           // out1 -> out2
    float* al_s1 = (float*)(w + 51200000);
    float* al_d1 = (float*)(w + 51600000);
    float* al_s2 = (float*)(w + 52000000);
    float* al_d2 = (float*)(w + 52200000);
    int*   deg   = (int*)(w + 52400000);
    int*   offp  = (int*)(w + 52600000);
    int*   cursor= (int*)(w + 52800064);
    int*   ssrc  = (int*)(w + 53000064);
    int*   bsum  = (int*)(w + 59400064);
    unsigned short* W2th = (unsigned short*)(w + 59401088);
    unsigned short* W2tl = W2th + 4096;
    unsigned short* W3th = W2th + 8192;
    unsigned short* W3tl = W2th + 12288;

    hipMemsetAsync(deg, 0, N_NODES * sizeof(int), stream);
    k_wprep<<<64, 64, 0, stream>>>(mW2, mW3, W2th, W2tl, W3th, W3tl);
    k1_h1<<<N_NODES, 128, 0, stream>>>(x, W1, as1, ad1, bufA, al_s1, al_d1);
    k_hist<<<(N_EDGES + 255) / 256, 256, 0, stream>>>(col, deg);
    k_scan1<<<(N_NODES + SCAN_B - 1) / SCAN_B, SCAN_B, 0, stream>>>(deg, offp, bsum);
    k_scan2<<<1, SCAN_B, 0, stream>>>(bsum, (N_NODES + SCAN_B - 1) / SCAN_B);
    k_scan3<<<(N_NODES + SCAN_B - 1) / SCAN_B, SCAN_B, 0, stream>>>(offp, bsum, cursor);
    k_scatter<<<(N_EDGES + 255) / 256, 256, 0, stream>>>(row, col, cursor, ssrc);
    k3_agg1<<<N_NODES / 4, 256, 0, stream>>>(bufA, al_s1, al_d1, b1, offp, ssrc, bufB);
    k4_h2<<<N_NODES / 4, 256, 0, stream>>>(bufB, W2, as2, ad2, bufA, al_s2, al_d2);
    k5_agg2<<<N_NODES / 4, 256, 0, stream>>>(bufA, al_s2, al_d2, b2, offp, ssrc, bufB);
    k6_uv<<<N_NODES / 4, 256, 0, stream>>>(bufB, mW1, mb1, bufA, bufA + N_NODES * 64);
    k7c_mlp<<<N_EDGES / 256, 256, 0, stream>>>(row, col, bufA, bufA + N_NODES * 64,
                                               W2th, W2tl, W3th, W3tl,
                                               mb2, mb3, mW4, mb4, out);
}

// Round 4
// 900.236 us; speedup vs baseline: 1.9709x; 1.1738x over previous
//
#include <hip/hip_runtime.h>
#include <hip/hip_bf16.h>
#include <math.h>

#define N_NODES 50000
#define N_EDGES 1600000
#define IN_DIM 16
#define HID 64

typedef __attribute__((ext_vector_type(8))) short short8v;
typedef __attribute__((ext_vector_type(16))) float f32x16;

union U32x4S8 { unsigned u[4]; short8v s; };

__device__ __forceinline__ float lrelu(float v) { return v > 0.f ? v : 0.2f * v; }

__device__ __forceinline__ float wave_reduce_sum(float v) {
    #pragma unroll
    for (int off = 32; off > 0; off >>= 1) v += __shfl_down(v, off, 64);
    return v;
}

__device__ __forceinline__ unsigned pk_bf16(float a, float b) {
    unsigned ua = (unsigned)__bfloat16_as_ushort(__float2bfloat16(a));
    unsigned ub = (unsigned)__bfloat16_as_ushort(__float2bfloat16(b));
    return ua | (ub << 16);
}

__device__ __forceinline__ void hilo2(float f0, float f1, unsigned& hw, unsigned& lw) {
    __hip_bfloat16 h0 = __float2bfloat16(f0), h1 = __float2bfloat16(f1);
    float r0 = __bfloat162float(h0), r1 = __bfloat162float(h1);
    hw = (unsigned)__bfloat16_as_ushort(h0) | ((unsigned)__bfloat16_as_ushort(h1) << 16);
    lw = pk_bf16(f0 - r0, f1 - r1);
}

// qs[i][h] = sum_c W1[i, h*64+c] * as1[h,c]  (and qd with ad1)
__global__ void k_qprep(const float* __restrict__ W1, const float* __restrict__ as1,
                        const float* __restrict__ ad1, float* __restrict__ qs, float* __restrict__ qd) {
    int t = threadIdx.x;
    if (t < 32) {
        int i = t >> 1, h = t & 1;
        float s = 0.f, d = 0.f;
        for (int c = 0; c < 64; c++) {
            float w = W1[i * 128 + h * 64 + c];
            s = fmaf(w, as1[h * 64 + c], s);
            d = fmaf(w, ad1[h * 64 + c], d);
        }
        qs[i * 2 + h] = s; qd[i * 2 + h] = d;
    }
}

// al_s1[n,h] = x[n,:] . qs[:,h]
__global__ void k1n(const float* __restrict__ x, const float* __restrict__ qs,
                    const float* __restrict__ qd, float* __restrict__ al_s, float* __restrict__ al_d) {
    int n = blockIdx.x * 256 + threadIdx.x;
    if (n >= N_NODES) return;
    float s0 = 0.f, s1 = 0.f, d0 = 0.f, d1 = 0.f;
    #pragma unroll
    for (int i = 0; i < IN_DIM; i++) {
        float xv = x[n * IN_DIM + i];
        s0 = fmaf(xv, qs[i * 2 + 0], s0);
        s1 = fmaf(xv, qs[i * 2 + 1], s1);
        d0 = fmaf(xv, qd[i * 2 + 0], d0);
        d1 = fmaf(xv, qd[i * 2 + 1], d1);
    }
    al_s[n * 2 + 0] = s0; al_s[n * 2 + 1] = s1;
    al_d[n * 2 + 0] = d0; al_d[n * 2 + 1] = d1;
}

// CSR build
__global__ void k_hist(const int* __restrict__ dst, int* __restrict__ deg) {
    int e = blockIdx.x * blockDim.x + threadIdx.x;
    if (e < N_EDGES) atomicAdd(&deg[dst[e]], 1);
}

#define SCAN_B 256
__global__ void k_scan1(const int* __restrict__ deg, int* __restrict__ off, int* __restrict__ bsum) {
    __shared__ int sh[SCAN_B];
    int gid = blockIdx.x * SCAN_B + threadIdx.x;
    int v = (gid < N_NODES) ? deg[gid] : 0;
    sh[threadIdx.x] = v;
    __syncthreads();
    for (int o = 1; o < SCAN_B; o <<= 1) {
        int t = (threadIdx.x >= o) ? sh[threadIdx.x - o] : 0;
        __syncthreads();
        sh[threadIdx.x] += t;
        __syncthreads();
    }
    int incl = sh[threadIdx.x];
    if (gid < N_NODES) off[gid] = incl - v;
    if (threadIdx.x == SCAN_B - 1) bsum[blockIdx.x] = incl;
}
__global__ void k_scan2(int* __restrict__ bsum, int nblocks) {
    __shared__ int sh[SCAN_B];
    int v = (threadIdx.x < nblocks) ? bsum[threadIdx.x] : 0;
    sh[threadIdx.x] = v;
    __syncthreads();
    for (int o = 1; o < SCAN_B; o <<= 1) {
        int t = (threadIdx.x >= o) ? sh[threadIdx.x - o] : 0;
        __syncthreads();
        sh[threadIdx.x] += t;
        __syncthreads();
    }
    if (threadIdx.x < nblocks) bsum[threadIdx.x] = sh[threadIdx.x] - v;
}
__global__ void k_scan3(int* __restrict__ off, const int* __restrict__ bsum, int* __restrict__ cursor) {
    int gid = blockIdx.x * SCAN_B + threadIdx.x;
    if (gid < N_NODES) {
        int o = off[gid] + bsum[blockIdx.x];
        off[gid] = o;
        cursor[gid] = o;
    }
    if (gid == 0) off[N_NODES] = N_EDGES;
}
// scatter edges into CSR order; also record dst and original edge id
__global__ void k_scatter3(const int* __restrict__ src, const int* __restrict__ dst,
                           int* __restrict__ cursor, int* __restrict__ ssrc,
                           int* __restrict__ sdst, int* __restrict__ eid) {
    int e = blockIdx.x * blockDim.x + threadIdx.x;
    if (e < N_EDGES) {
        int d = dst[e];
        int pos = atomicAdd(&cursor[d], 1);
        ssrc[pos] = src[e];
        sdst[pos] = d;
        eid[pos] = e;
    }
}

// K3n: layer-1 aggregation in x-space (16-dim), online softmax.
// 2 dsts per wave; 32 lanes per dst: head = (lane&31)>>4, ch = lane&15.
__global__ void k3n(const float* __restrict__ x, const float* __restrict__ als,
                    const float* __restrict__ ald, const int* __restrict__ off,
                    const int* __restrict__ ssrc, float* __restrict__ accx,
                    float* __restrict__ denb) {
    int wid = threadIdx.x >> 6, lane = threadIdx.x & 63;
    int half = lane >> 5, sub = lane & 31, head = sub >> 4, ch = sub & 15;
    int d = blockIdx.x * 8 + wid * 2 + half;
    if (d >= N_NODES) return;
    int beg = off[d], end = off[d + 1];
    float adv = ald[d * 2 + head];
    float m = lrelu(als[d * 2 + head] + adv);
    float den = 1.f;
    float acc = x[d * IN_DIM + ch];
    for (int i = beg; i < end; i++) {
        int s = ssrc[i];
        float e = lrelu(als[s * 2 + head] + adv);
        float xv = x[s * IN_DIM + ch];
        float n2 = fmaxf(m, e);
        float f = __expf(m - n2), w = __expf(e - n2);
        den = den * f + w;
        acc = acc * f + w * xv;
        m = n2;
    }
    accx[d * 32 + sub] = acc;
    if ((sub & 15) == 0) denb[d * 2 + head] = den;
}

// K4n: fused out1-expand (accx @ W1, /den, +b1, relu) then @ W2 -> h2, al_s2/al_d2.
__global__ __launch_bounds__(256) void k4n(
    const float* __restrict__ accx, const float* __restrict__ denb,
    const float* __restrict__ W1, const float* __restrict__ b1,
    const float* __restrict__ W2, const float* __restrict__ as2, const float* __restrict__ ad2,
    float* __restrict__ h2, float* __restrict__ al_s, float* __restrict__ al_d) {
    __shared__ float W1s[16 * 128];
    __shared__ float W2s[128 * 64];
    __shared__ float st[4][160];   // [0..31]=accx, [32..159]=tmp128
    for (int t = threadIdx.x; t < 16 * 128; t += 256) W1s[t] = W1[t];
    for (int t = threadIdx.x; t < 128 * 64; t += 256) W2s[t] = W2[t];
    __syncthreads();
    int wid = threadIdx.x >> 6, lane = threadIdx.x & 63;
    int n = blockIdx.x * 4 + wid;
    if (n >= N_NODES) return;
    if (lane < 32) st[wid][lane] = accx[n * 32 + lane];
    float den0 = denb[n * 2], den1 = denb[n * 2 + 1];
    float ta = 0.f, tb = 0.f;
    #pragma unroll
    for (int i = 0; i < 16; i++) {
        ta = fmaf(st[wid][i],      W1s[i * 128 + lane],      ta);
        tb = fmaf(st[wid][16 + i], W1s[i * 128 + 64 + lane], tb);
    }
    ta = fmaxf(ta / den0 + b1[lane], 0.f);
    tb = fmaxf(tb / den1 + b1[64 + lane], 0.f);
    st[wid][32 + lane] = ta;
    st[wid][96 + lane] = tb;
    float acc = 0.f;
    #pragma unroll 8
    for (int k = 0; k < 128; k++) acc = fmaf(st[wid][32 + k], W2s[k * 64 + lane], acc);
    h2[n * 64 + lane] = acc;
    float ps = wave_reduce_sum(acc * as2[lane]);
    float pd = wave_reduce_sum(acc * ad2[lane]);
    if (lane == 0) { al_s[n] = ps; al_d[n] = pd; }
}

// K5n: fused layer-2 aggregation (online softmax) + out2 @ mW1 -> U(+mb1), V.
__global__ __launch_bounds__(256) void k5n(
    const float* __restrict__ h2, const float* __restrict__ als, const float* __restrict__ ald,
    const float* __restrict__ b2, const float* __restrict__ mW1, const float* __restrict__ mb1,
    const int* __restrict__ off, const int* __restrict__ ssrc,
    float* __restrict__ U, float* __restrict__ V) {
    __shared__ float Ws[128 * 64];
    __shared__ float o2s[4][64];
    for (int t = threadIdx.x; t < 128 * 64; t += 256) Ws[t] = mW1[t];
    __syncthreads();
    int wid = threadIdx.x >> 6, lane = threadIdx.x & 63;
    int d = blockIdx.x * 4 + wid;
    if (d >= N_NODES) return;
    int beg = off[d], end = off[d + 1];
    float adv = ald[d];
    float m = lrelu(als[d] + adv);
    float den = 1.f;
    float acc = h2[d * 64 + lane];
    for (int i = beg; i < end; i++) {
        int s = ssrc[i];
        float e = lrelu(als[s] + adv);
        float hv = h2[s * 64 + lane];
        float n2 = fmaxf(m, e);
        float f = __expf(m - n2), w = __expf(e - n2);
        den = den * f + w;
        acc = acc * f + w * hv;
        m = n2;
    }
    float o2 = fmaxf(acc / den + b2[lane], 0.f);
    o2s[wid][lane] = o2;
    float au = mb1[lane], av = 0.f;
    #pragma unroll 8
    for (int k = 0; k < 64; k++) {
        float ov = o2s[wid][k];
        au = fmaf(ov, Ws[k * 64 + lane], au);
        av = fmaf(ov, Ws[(64 + k) * 64 + lane], av);
    }
    U[d * 64 + lane] = au;
    V[d * 64 + lane] = av;
}

// weight prep: W{2,3}t[b][t] = mW{2,3}[t*64+b] split into bf16 hi/lo tables
__global__ void k_wprep(const float* __restrict__ mW2, const float* __restrict__ mW3,
                        unsigned short* __restrict__ W2th, unsigned short* __restrict__ W2tl,
                        unsigned short* __restrict__ W3th, unsigned short* __restrict__ W3tl) {
    int b = blockIdx.x, t = threadIdx.x;
    float w2 = mW2[t * 64 + b];
    __hip_bfloat16 h2 = __float2bfloat16(w2);
    W2th[b * 64 + t] = __bfloat16_as_ushort(h2);
    W2tl[b * 64 + t] = __bfloat16_as_ushort(__float2bfloat16(w2 - __bfloat162float(h2)));
    float w3 = mW3[t * 64 + b];
    __hip_bfloat16 h3 = __float2bfloat16(w3);
    W3th[b * 64 + t] = __bfloat16_as_ushort(h3);
    W3tl[b * 64 + t] = __bfloat16_as_ushort(__float2bfloat16(w3 - __bfloat162float(h3)));
}

// K7d: edge MLP via MFMA, edges in CSR (dst-sorted) order for V locality; out via eid.
__global__ __launch_bounds__(256) void k7d(
    const int* __restrict__ ssrc, const int* __restrict__ sdst, const int* __restrict__ eid,
    const float* __restrict__ Ub, const float* __restrict__ Vb,
    const unsigned short* __restrict__ W2th, const unsigned short* __restrict__ W2tl,
    const unsigned short* __restrict__ W3th, const unsigned short* __restrict__ W3tl,
    const float* __restrict__ mb2, const float* __restrict__ mb3,
    const float* __restrict__ mW4, const float* __restrict__ mb4,
    float* __restrict__ out)
{
    const int wid = threadIdx.x >> 6, lane = threadIdx.x & 63;
    const int ebase = blockIdx.x * 256 + wid * 64;
    const int l31 = lane & 31;
    const int h = lane >> 5;
    const int ksub = h * 8;

    int rfull = ssrc[ebase + lane];
    int cfull = sdst[ebase + lane];
    int efull = eid[ebase + lane];
    float b4v = mb4[0];

    #pragma unroll 1
    for (int nB = 0; nB < 2; nB++) {
        int rA = __shfl(rfull, nB * 32 + l31, 64);
        int cA = __shfl(cfull, nB * 32 + l31, 64);
        const float* urow = Ub + rA * 64 + ksub;
        const float* vrow = Vb + cA * 64 + ksub;

        // layer-2 accumulators, bias-initialized
        f32x16 c2[2];
        #pragma unroll
        for (int mA = 0; mA < 2; mA++)
            #pragma unroll
            for (int r = 0; r < 16; r++)
                c2[mA][r] = mb2[mA * 32 + (r & 3) + 8 * (r >> 2) + 4 * h];

        #pragma unroll
        for (int kb = 0; kb < 4; kb++) {
            float4 u0 = *(const float4*)(urow + kb * 16);
            float4 u1 = *(const float4*)(urow + kb * 16 + 4);
            float4 v0 = *(const float4*)(vrow + kb * 16);
            float4 v1 = *(const float4*)(vrow + kb * 16 + 4);
            float z[8];
            z[0] = fmaxf(u0.x + v0.x, 0.f); z[1] = fmaxf(u0.y + v0.y, 0.f);
            z[2] = fmaxf(u0.z + v0.z, 0.f); z[3] = fmaxf(u0.w + v0.w, 0.f);
            z[4] = fmaxf(u1.x + v1.x, 0.f); z[5] = fmaxf(u1.y + v1.y, 0.f);
            z[6] = fmaxf(u1.z + v1.z, 0.f); z[7] = fmaxf(u1.w + v1.w, 0.f);
            U32x4S8 bh, bl;
            #pragma unroll
            for (int q = 0; q < 4; q++) hilo2(z[2 * q], z[2 * q + 1], bh.u[q], bl.u[q]);
            #pragma unroll
            for (int mA = 0; mA < 2; mA++) {
                const int wrow = (mA * 32 + l31) * 64 + kb * 16 + ksub;
                short8v ah = *(const short8v*)(W2th + wrow);
                short8v al = *(const short8v*)(W2tl + wrow);
                c2[mA] = __builtin_amdgcn_mfma_f32_32x32x16_bf16(ah, bh.s, c2[mA], 0, 0, 0);
                c2[mA] = __builtin_amdgcn_mfma_f32_32x32x16_bf16(al, bh.s, c2[mA], 0, 0, 0);
                c2[mA] = __builtin_amdgcn_mfma_f32_32x32x16_bf16(ah, bl.s, c2[mA], 0, 0, 0);
                c2[mA] = __builtin_amdgcn_mfma_f32_32x32x16_bf16(al, bl.s, c2[mA], 0, 0, 0);
            }
        }

        // layer-3 accumulators, bias-initialized
        f32x16 c3[2];
        #pragma unroll
        for (int mA = 0; mA < 2; mA++)
            #pragma unroll
            for (int r = 0; r < 16; r++)
                c3[mA][r] = mb3[mA * 32 + (r & 3) + 8 * (r >> 2) + 4 * h];

        // per-kbp: refragment relu(c2) -> B operand, immediately consume with MFMAs
        #pragma unroll
        for (int kbp = 0; kbp < 4; kbp++) {
            const int mAs = kbp >> 1, kbl = kbp & 1;
            float e[8];
            #pragma unroll
            for (int b = 0; b < 4; b++) {
                float u = fmaxf(c2[mAs][8 * kbl + b], 0.f);
                float v = fmaxf(c2[mAs][8 * kbl + 4 + b], 0.f);
                float su = __shfl_xor(u, 32, 64);
                float sv = __shfl_xor(v, 32, 64);
                e[b]     = h ? sv : u;
                e[4 + b] = h ? v : su;
            }
            U32x4S8 bh, bl;
            #pragma unroll
            for (int q = 0; q < 4; q++) hilo2(e[2 * q], e[2 * q + 1], bh.u[q], bl.u[q]);
            #pragma unroll
            for (int mA = 0; mA < 2; mA++) {
                const int wrow = (mA * 32 + l31) * 64 + kbp * 16 + ksub;
                short8v ah = *(const short8v*)(W3th + wrow);
                short8v al = *(const short8v*)(W3tl + wrow);
                c3[mA] = __builtin_amdgcn_mfma_f32_32x32x16_bf16(ah, bh.s, c3[mA], 0, 0, 0);
                c3[mA] = __builtin_amdgcn_mfma_f32_32x32x16_bf16(al, bh.s, c3[mA], 0, 0, 0);
                c3[mA] = __builtin_amdgcn_mfma_f32_32x32x16_bf16(ah, bl.s, c3[mA], 0, 0, 0);
                c3[mA] = __builtin_amdgcn_mfma_f32_32x32x16_bf16(al, bl.s, c3[mA], 0, 0, 0);
            }
        }

        float p = 0.f;
        #pragma unroll
        for (int mA = 0; mA < 2; mA++)
            #pragma unroll
            for (int r = 0; r < 16; r++)
                p = fmaf(fmaxf(c3[mA][r], 0.f), mW4[mA * 32 + (r & 3) + 8 * (r >> 2) + 4 * h], p);
        p += __shfl_xor(p, 32, 64);
        int oidx = __shfl(efull, nB * 32 + lane, 64);
        if (lane < 32) out[oidx] = p + b4v;
    }
}

extern "C" void kernel_launch(void* const* d_in, const int* in_sizes, int n_in,
                              void* d_out, int out_size, void* d_ws, size_t ws_size,
                              hipStream_t stream) {
    const float* x   = (const float*)d_in[0];
    const int*   ei  = (const int*)d_in[1];
    const float* W1  = (const float*)d_in[2];
    const float* as1 = (const float*)d_in[3];
    const float* ad1 = (const float*)d_in[4];
    const float* b1  = (const float*)d_in[5];
    const float* W2  = (const float*)d_in[6];
    const float* as2 = (const float*)d_in[7];
    const float* ad2 = (const float*)d_in[8];
    const float* b2  = (const float*)d_in[9];
    const float* mW1 = (const float*)d_in[10];
    const float* mb1 = (const float*)d_in[11];
    const float* mW2 = (const float*)d_in[12];
    const float* mb2 = (const float*)d_in[13];
    const float* mW3 = (const float*)d_in[14];
    const float* mb3 = (const float*)d_in[15];
    const float* mW4 = (const float*)d_in[16];
    const float* mb4 = (const float*)d_in[17];
    float* out = (float*)d_out;
    const int* row = ei;             // src
    const int* col = ei + N_EDGES;   // dst

    char* w = (char*)d_ws;
    float* U     = (float*)w;                         // 12.8 MB, live k5->k7
    float* V     = (float*)(w + 12800000);            // 12.8 MB, live k5->k7
    float* h2    = (float*)(w + 25600000);            // 12.8 MB, live k4->k5
    int*   ssrc  = (int*)(w + 38400000);              // 6.4 MB
    int*   sdst  = (int*)(w + 44800000);              // 6.4 MB
    int*   eid   = (int*)(w + 51200000);              // 6.4 MB
    int*   deg   = (int*)(w + 57600000);              // 0.2 MB
    int*   offp  = (int*)(w + 57800000);              // 0.2 MB + 4
    int*   cursor= (int*)(w + 58000064);              // 0.2 MB
    float* al_s2 = (float*)(w + 58200064);
    float* al_d2 = (float*)(w + 58400064);
    int*   bsum  = (int*)(w + 58600064);              // 1 KB
    float* qs    = (float*)(w + 58601088);            // 128 B
    float* qd    = (float*)(w + 58601216);            // 128 B
    unsigned short* W2th = (unsigned short*)(w + 58601344);
    unsigned short* W2tl = W2th + 4096;
    unsigned short* W3th = W2th + 8192;
    unsigned short* W3tl = W2th + 12288;
    // overlays inside U region (dead before k5n writes U):
    float* accx  = U;                                 // 6.4 MB, live k3->k4
    float* denb  = (float*)(w + 6400000);             // 0.4 MB, live k3->k4
    float* al_s1 = (float*)(w + 6800000);             // 0.4 MB, live k1->k3
    float* al_d1 = (float*)(w + 7200000);             // 0.4 MB, live k1->k3

    hipMemsetAsync(deg, 0, N_NODES * sizeof(int), stream);
    k_qprep<<<1, 64, 0, stream>>>(W1, as1, ad1, qs, qd);
    k_wprep<<<64, 64, 0, stream>>>(mW2, mW3, W2th, W2tl, W3th, W3tl);
    k1n<<<(N_NODES + 255) / 256, 256, 0, stream>>>(x, qs, qd, al_s1, al_d1);
    k_hist<<<(N_EDGES + 255) / 256, 256, 0, stream>>>(col, deg);
    k_scan1<<<(N_NODES + SCAN_B - 1) / SCAN_B, SCAN_B, 0, stream>>>(deg, offp, bsum);
    k_scan2<<<1, SCAN_B, 0, stream>>>(bsum, (N_NODES + SCAN_B - 1) / SCAN_B);
    k_scan3<<<(N_NODES + SCAN_B - 1) / SCAN_B, SCAN_B, 0, stream>>>(offp, bsum, cursor);
    k_scatter3<<<(N_EDGES + 255) / 256, 256, 0, stream>>>(row, col, cursor, ssrc, sdst, eid);
    k3n<<<N_NODES / 8, 256, 0, stream>>>(x, al_s1, al_d1, offp, ssrc, accx, denb);
    k4n<<<N_NODES / 4, 256, 0, stream>>>(accx, denb, W1, b1, W2, as2, ad2, h2, al_s2, al_d2);
    k5n<<<N_NODES / 4, 256, 0, stream>>>(h2, al_s2, al_d2, b2, mW1, mb1, offp, ssrc, U, V);
    k7d<<<N_EDGES / 256, 256, 0, stream>>>(ssrc, sdst, eid, U, V,
                                           W2th, W2tl, W3th, W3tl,
                                           mb2, mb3, mW4, mb4, out);
}